// Round 2
// baseline (1108.014 us; speedup 1.0000x reference)
//
#include <hip/hip_runtime.h>

#define NH 6
#define HD 32
#define WIN 8
#define NWH 32
#define HWSZ 65536
#define SCALE 0.17677669529663687f  // 32^-0.5

// One wave (64 threads) per (batch, window, head).
// lane = q spatial position within the 8x8 window; att row lives in registers.
__global__ __launch_bounds__(64, 2)
void swin_attn_kernel(const float* __restrict__ x,
                      const float* __restrict__ rpb,
                      float* __restrict__ out) {
  __shared__ float Kt[HD * 64];   // Kt[d][s], s = iy*8+ix
  __shared__ float Vt[HD * 64];   // Vt[d][s]
  __shared__ float rpb_s[228];    // this head's rpb column (225 used)

  // XCD-chunked bijective swizzle: 24576 blocks, 24576 % 8 == 0
  const int raw = (int)blockIdx.x;
  const int lid = (raw & 7) * 3072 + (raw >> 3);
  const int ww = lid & 31;
  int t = lid >> 5;
  const int nh = t % NH;
  t /= NH;                 // t = b*32 + wh
  const int wh = t & 31;
  const int b  = t >> 5;

  const int lane = threadIdx.x;

  // ---- stage K, V into LDS transposed [d][s] via global_load_lds (16B/lane) ----
  // instr i: element e = i*256 + lane*4 ; d = i*4 + (lane>>4) ; s0 = (lane&15)*4
  // SHIFT=4 means every 4-float chunk is contiguous in w even at the wrap.
  {
    const int dly = lane >> 4;            // 0..3
    const int s0  = (lane & 15) << 2;     // 0,4,...,60
    const int iy  = s0 >> 3;
    const int ix0 = s0 & 7;               // 0 or 4
    const int sh  = (wh * WIN + 4 + iy) & 255;
    const int sw  = (ww * WIN + 4 + ix0) & 255;
    const size_t base = (size_t)(b * 576 + nh * HD + dly) * HWSZ + (size_t)sh * 256 + sw;
    const float* gk = x + base + (size_t)192 * HWSZ;   // c3 = 1 (K)
    const float* gv = x + base + (size_t)384 * HWSZ;   // c3 = 2 (V)
#pragma unroll
    for (int i = 0; i < 8; ++i) {
      __builtin_amdgcn_global_load_lds(
          (const __attribute__((address_space(1))) void*)(gk + (size_t)i * 4 * HWSZ),
          (__attribute__((address_space(3))) void*)(&Kt[i * 256]), 16, 0, 0);
      __builtin_amdgcn_global_load_lds(
          (const __attribute__((address_space(1))) void*)(gv + (size_t)i * 4 * HWSZ),
          (__attribute__((address_space(3))) void*)(&Vt[i * 256]), 16, 0, 0);
    }
  }

  // rpb column for this head into LDS
  for (int r = lane; r < 225; r += 64) rpb_s[r] = rpb[r * NH + nh];

  // ---- per-lane Q row straight from global (coalesces as 32B segments) ----
  const int qy = lane >> 3, qx = lane & 7;
  const int sh = (wh * WIN + 4 + qy) & 255;
  const int sw = (ww * WIN + 4 + qx) & 255;
  const float* qbase = x + (size_t)(b * 576 + nh * HD) * HWSZ + (size_t)sh * 256 + sw;
  float Qr[HD];
#pragma unroll
  for (int d = 0; d < HD; ++d) Qr[d] = qbase[(size_t)d * HWSZ];

  __syncthreads();   // drains vmcnt (global_load_lds) before LDS reads

  // ---- QK^T: att[k] = sum_d Q[q][d] * K[k][d], K rows broadcast from LDS ----
  float att[64];
#pragma unroll
  for (int k = 0; k < 64; ++k) att[k] = 0.f;
#pragma unroll 2
  for (int d = 0; d < HD; ++d) {
    const float qd = Qr[d];
    const float4* kp = (const float4*)&Kt[d * 64];
#pragma unroll
    for (int j = 0; j < 16; ++j) {
      const float4 kv = kp[j];
      att[4*j+0] = fmaf(qd, kv.x, att[4*j+0]);
      att[4*j+1] = fmaf(qd, kv.y, att[4*j+1]);
      att[4*j+2] = fmaf(qd, kv.z, att[4*j+2]);
      att[4*j+3] = fmaf(qd, kv.w, att[4*j+3]);
    }
  }

  // ---- scale + relative position bias + shift mask + row max ----
  const bool eh = (wh == NWH - 1), ew = (ww == NWH - 1);
  const int rq = (eh ? 1 + (qy >> 2) : 0) * 3 + (ew ? 1 + (qx >> 2) : 0);
  const int qoff = (qy + 7) * 15 + (qx + 7);
  float m = -1e30f;
#pragma unroll
  for (int k = 0; k < 64; ++k) {
    const int ky = k >> 3, kx = k & 7;
    float a = fmaf(att[k], SCALE, rpb_s[qoff - (ky * 15 + kx)]);
    const int rk = (eh ? 1 + (ky >> 2) : 0) * 3 + (ew ? 1 + (kx >> 2) : 0);
    a += (rk == rq) ? 0.f : -100.f;
    att[k] = a;
    m = fmaxf(m, a);
  }

  // ---- softmax (fully in-lane) ----
  float p0 = 0.f, p1 = 0.f, p2 = 0.f, p3 = 0.f;
#pragma unroll
  for (int k = 0; k < 64; k += 4) {
    att[k+0] = __expf(att[k+0] - m); p0 += att[k+0];
    att[k+1] = __expf(att[k+1] - m); p1 += att[k+1];
    att[k+2] = __expf(att[k+2] - m); p2 += att[k+2];
    att[k+3] = __expf(att[k+3] - m); p3 += att[k+3];
  }
  const float rsum = 1.f / (p0 + p1 + p2 + p3);

  // ---- PV: out[q][dv] = (sum_k att[k] * V[k][dv]) * rsum, V rows broadcast ----
  float* obase = out + (size_t)(b * 192 + nh * HD) * HWSZ + (size_t)sh * 256 + sw;
#pragma unroll 2
  for (int dv = 0; dv < HD; ++dv) {
    const float4* vp = (const float4*)&Vt[dv * 64];
    float a0 = 0.f, a1 = 0.f, a2 = 0.f, a3 = 0.f;
#pragma unroll
    for (int j = 0; j < 16; ++j) {
      const float4 vv = vp[j];
      a0 = fmaf(att[4*j+0], vv.x, a0);
      a1 = fmaf(att[4*j+1], vv.y, a1);
      a2 = fmaf(att[4*j+2], vv.z, a2);
      a3 = fmaf(att[4*j+3], vv.w, a3);
    }
    obase[(size_t)dv * HWSZ] = (a0 + a1 + a2 + a3) * rsum;
  }
}

extern "C" void kernel_launch(void* const* d_in, const int* in_sizes, int n_in,
                              void* d_out, int out_size, void* d_ws, size_t ws_size,
                              hipStream_t stream) {
  const float* x   = (const float*)d_in[0];
  const float* rpb = (const float*)d_in[1];
  float* out = (float*)d_out;
  dim3 grid(4 * 32 * 32 * NH);   // 24576 blocks: (b, wh, nh, ww), ww fastest
  dim3 block(64);
  hipLaunchKernelGGL(swin_attn_kernel, grid, block, 0, stream, x, rpb, out);
}

// Round 4
// 1006.242 us; speedup vs baseline: 1.1011x; 1.1011x over previous
//
#include <hip/hip_runtime.h>

#define NH 6
#define HWSZ 65536
#define SCALE 0.17677669529663687f  // 32^-0.5

typedef __attribute__((ext_vector_type(8)))  short short8t;   // 8 bf16 = 4 VGPR (MFMA frag)
typedef __attribute__((ext_vector_type(16))) float f32x16;    // MFMA 32x32 accumulator
typedef __attribute__((ext_vector_type(4)))  unsigned int uint4t;

__device__ __forceinline__ unsigned int pack2(float a, float b) {
  // low short = bf16-trunc(a), high short = bf16-trunc(b)
  return (__float_as_uint(a) >> 16) | (__float_as_uint(b) & 0xffff0000u);
}
__device__ __forceinline__ float btrunc_f(float a) {   // value of truncated-bf16(a)
  return __uint_as_float(__float_as_uint(a) & 0xffff0000u);
}
__device__ __forceinline__ float resid(float a) { return a - btrunc_f(a); }

// split 8 floats into hi/lo bf16 fragments (truncation split: hi+lo == x to ~2^-16 rel)
__device__ __forceinline__ void split8(const float (&f)[8], short8t& h, short8t& l) {
  uint4t hw, lw;
#pragma unroll
  for (int i = 0; i < 4; ++i) {
    const float a = f[2*i], c = f[2*i+1];
    hw[i] = pack2(a, c);
    lw[i] = pack2(resid(a), resid(c));
  }
  h = __builtin_bit_cast(short8t, hw);
  l = __builtin_bit_cast(short8t, lw);
}

// One wave per (b, wh, ww, nh). Swapped-operand MFMA attention:
//   att^T(64x64) = K(64x32) · Q^T(32x64)   -> softmax lane-local (1 xor-32 exchange)
//   out^T(32x64) = V^T(32x64) · P^T(64x64)
// 32x32x16 layouts: A lane: m=lane&31, k=8*(lane>>5)+e ; B lane: n=lane&31, same k;
// C: col=lane&31, row=(r&3)+8*(r>>2)+4*(lane>>5)  [verified m74/m101]
__global__ __launch_bounds__(64, 2)
void swin_attn_mfma(const float* __restrict__ x,
                    const float* __restrict__ rpb,
                    float* __restrict__ out) {
  __shared__ float Vt[2048];     // [d][chunk'][8], chunk' = (s>>3) ^ (d&7)  (XOR swizzle)
  __shared__ float rpb_s[232];   // this head's rpb column (225 used)

  // XCD-chunked bijective swizzle (24576 % 8 == 0)
  const int raw = (int)blockIdx.x;
  const int lid = (raw & 7) * 3072 + (raw >> 3);
  const int ww = lid & 31;
  int t = lid >> 5;
  const int nh = t % NH; t /= NH;
  const int wh = t & 31;
  const int b  = t >> 5;

  const int lane = (int)threadIdx.x;
  const int lo = lane & 31, hi = lane >> 5;

  // ---- V staging: global -> LDS, dest linear, source pre-swizzled (rule #21) ----
  // dest pos p = i*256 + lane*4 : d = i*4 + (lane>>4), chunk' = (lane&15)>>1, off0=(lane&1)*4
  // content: V[s = (chunk'^(d&7))*8 + off][d]; 16B source chunks are w-contiguous, wrap-safe
  {
    const int dly = lane >> 4;
    const int chp = (lane & 15) >> 1;
    const int off0 = (lane & 1) * 4;
    const int s0e = ((chp ^ dly) << 3) + off0;        // even i: d&7 = dly
    const int s0o = ((chp ^ (4 + dly)) << 3) + off0;  // odd  i: d&7 = 4+dly
    const size_t cb = (size_t)(b * 576 + 384 + nh * 32 + dly) * HWSZ;
    const float* gve = x + cb + (size_t)(((wh*8+4+(s0e>>3)) & 255) * 256 + ((ww*8+4+(s0e&7)) & 255));
    const float* gvo = x + cb + (size_t)(((wh*8+4+(s0o>>3)) & 255) * 256 + ((ww*8+4+(s0o&7)) & 255));
#pragma unroll
    for (int i = 0; i < 8; ++i) {
      const float* src = (i & 1) ? gvo : gve;
      __builtin_amdgcn_global_load_lds(
          (const __attribute__((address_space(1))) void*)(src + (size_t)i * 4 * HWSZ),
          (__attribute__((address_space(3))) void*)(&Vt[i * 256]), 16, 0, 0);
    }
  }
  for (int r = lane; r < 225; r += 64) rpb_s[r] = rpb[r * NH + nh];

  // ---- shared pixel coords: q = 32*nt + lo and k-spatial s = 32*mt + lo use same sets ----
  const int iy = lo >> 3, ix = lo & 7;
  const int sh0 = (wh*8 + 4 + iy) & 255;       // tile 0 (rows 0..3)
  const int sh1 = (wh*8 + 8 + iy) & 255;       // tile 1 (rows 4..7)
  const int sw  = (ww*8 + 4 + ix) & 255;
  const size_t pix0 = (size_t)sh0 * 256 + sw;
  const size_t pix1 = (size_t)sh1 * 256 + sw;
  const size_t qcb = (size_t)(b * 576 + nh * 32) * HWSZ;
  const size_t kcb = qcb + (size_t)192 * HWSZ;

  // ---- load Q/K fragments straight from global (per-lane scalar, 8x32B segs/inst) ----
  short8t qh[2][2], ql[2][2], kh[2][2], kl[2][2];   // [ks][tile]
#pragma unroll
  for (int ks = 0; ks < 2; ++ks) {
#pragma unroll
    for (int tt = 0; tt < 2; ++tt) {
      const size_t pp = tt ? pix1 : pix0;
      float f[8], g[8];
#pragma unroll
      for (int e = 0; e < 8; ++e) {
        const size_t dof = (size_t)(ks*16 + hi*8 + e) * HWSZ;
        f[e] = x[qcb + dof + pp];
        g[e] = x[kcb + dof + pp];
      }
      split8(f, qh[ks][tt], ql[ks][tt]);
      split8(g, kh[ks][tt], kl[ks][tt]);
    }
  }

  // ---- QK^T: acc[mt][nt] = K·Q^T with 3-product fp32-emulation ----
  f32x16 acc[2][2];
#pragma unroll
  for (int mt = 0; mt < 2; ++mt)
#pragma unroll
    for (int nt = 0; nt < 2; ++nt)
#pragma unroll
      for (int r = 0; r < 16; ++r) acc[mt][nt][r] = 0.f;

#pragma unroll
  for (int ks = 0; ks < 2; ++ks)
#pragma unroll
    for (int mt = 0; mt < 2; ++mt)
#pragma unroll
      for (int nt = 0; nt < 2; ++nt) {
        acc[mt][nt] = __builtin_amdgcn_mfma_f32_32x32x16_bf16(kh[ks][mt], qh[ks][nt], acc[mt][nt], 0, 0, 0);
        acc[mt][nt] = __builtin_amdgcn_mfma_f32_32x32x16_bf16(kh[ks][mt], ql[ks][nt], acc[mt][nt], 0, 0, 0);
        acc[mt][nt] = __builtin_amdgcn_mfma_f32_32x32x16_bf16(kl[ks][mt], qh[ks][nt], acc[mt][nt], 0, 0, 0);
      }

  __syncthreads();   // staging + rpb writes complete before LDS reads below

  // ---- scale + rpb + shift mask + row max (value (mt,nt,r): q=32nt+lo, k=32mt+4hi+(r&3)+8(r>>2)) ----
  const bool eh = (wh == 31), ew = (ww == 31);
  float mrow[2] = {-1e30f, -1e30f};
#pragma unroll
  for (int nt = 0; nt < 2; ++nt) {
    const int qyy = 4*nt + iy;
    const int rq = (eh ? 1 + (qyy >> 2) : 0) * 3 + (ew ? 1 + (ix >> 2) : 0);
    const int qoff = (qyy + 7) * 15 + (ix + 7);
#pragma unroll
    for (int mt = 0; mt < 2; ++mt)
#pragma unroll
      for (int r = 0; r < 16; ++r) {
        const int ky = 4*mt + (r >> 2);
        const int kx = 4*hi + (r & 3);
        float a = fmaf(acc[mt][nt][r], SCALE, rpb_s[qoff - ky*15 - kx]);
        const int rk = (eh ? 1 + (ky >> 2) : 0) * 3 + (ew ? 1 + (kx >> 2) : 0);
        a += (rk == rq) ? 0.f : -100.f;
        acc[mt][nt][r] = a;
        mrow[nt] = fmaxf(mrow[nt], a);
      }
  }
  mrow[0] = fmaxf(mrow[0], __shfl_xor(mrow[0], 32));
  mrow[1] = fmaxf(mrow[1], __shfl_xor(mrow[1], 32));

  float sum0 = 0.f, sum1 = 0.f;
#pragma unroll
  for (int mt = 0; mt < 2; ++mt)
#pragma unroll
    for (int r = 0; r < 16; ++r) {
      const float p0 = __expf(acc[mt][0][r] - mrow[0]);
      const float p1 = __expf(acc[mt][1][r] - mrow[1]);
      acc[mt][0][r] = p0; sum0 += p0;
      acc[mt][1][r] = p1; sum1 += p1;
    }
  sum0 += __shfl_xor(sum0, 32);
  sum1 += __shfl_xor(sum1, 32);
  const float rs0 = 1.f / sum0, rs1 = 1.f / sum1;

  // ---- PV: out^T = V^T · P^T ; P^T B-frags built via one xor-32 exchange per quad ----
  f32x16 oacc[2];
#pragma unroll
  for (int r = 0; r < 16; ++r) { oacc[0][r] = 0.f; oacc[1][r] = 0.f; }

#pragma unroll
  for (int ks2 = 0; ks2 < 4; ++ks2) {
    const int mt = ks2 >> 1, bs = (ks2 & 1) * 8;
    // V A-frag from swizzled LDS: element e -> V[s=16ks2+8hi+e][d=lo]
    float vf[8];
    {
      const int chp = (2*ks2 + hi) ^ (lo & 7);
      const float4 v0 = *(const float4*)&Vt[lo*64 + chp*8];
      const float4 v1 = *(const float4*)&Vt[lo*64 + chp*8 + 4];
      vf[0]=v0.x; vf[1]=v0.y; vf[2]=v0.z; vf[3]=v0.w;
      vf[4]=v1.x; vf[5]=v1.y; vf[6]=v1.z; vf[7]=v1.w;
    }
    short8t vh, vl; split8(vf, vh, vl);
#pragma unroll
    for (int nt = 0; nt < 2; ++nt) {
      // quadA: r = bs+0..3 (k = 16ks2 + 4hi + 0..3), quadB: r = bs+4..7 (k = +8)
      const float a0 = acc[mt][nt][bs+0], a1 = acc[mt][nt][bs+1];
      const float a2 = acc[mt][nt][bs+2], a3 = acc[mt][nt][bs+3];
      const float b0 = acc[mt][nt][bs+4], b1 = acc[mt][nt][bs+5];
      const float b2 = acc[mt][nt][bs+6], b3 = acc[mt][nt][bs+7];
      const unsigned int Ah0 = pack2(a0, a1), Ah1 = pack2(a2, a3);
      const unsigned int Bh0 = pack2(b0, b1), Bh1 = pack2(b2, b3);
      const unsigned int Al0 = pack2(resid(a0), resid(a1)), Al1 = pack2(resid(a2), resid(a3));
      const unsigned int Bl0 = pack2(resid(b0), resid(b1)), Bl1 = pack2(resid(b2), resid(b3));
      const unsigned int xAh0 = __shfl_xor(Ah0, 32), xAh1 = __shfl_xor(Ah1, 32);
      const unsigned int xBh0 = __shfl_xor(Bh0, 32), xBh1 = __shfl_xor(Bh1, 32);
      const unsigned int xAl0 = __shfl_xor(Al0, 32), xAl1 = __shfl_xor(Al1, 32);
      const unsigned int xBl0 = __shfl_xor(Bl0, 32), xBl1 = __shfl_xor(Bl1, 32);
      uint4t wh4, wl4;
      wh4[0] = hi ? xBh0 : Ah0;  wh4[1] = hi ? xBh1 : Ah1;
      wh4[2] = hi ? Bh0 : xAh0;  wh4[3] = hi ? Bh1 : xAh1;
      wl4[0] = hi ? xBl0 : Al0;  wl4[1] = hi ? xBl1 : Al1;
      wl4[2] = hi ? Bl0 : xAl0;  wl4[3] = hi ? Bl1 : xAl1;
      const short8t pbh = __builtin_bit_cast(short8t, wh4);
      const short8t pbl = __builtin_bit_cast(short8t, wl4);
      oacc[nt] = __builtin_amdgcn_mfma_f32_32x32x16_bf16(vh, pbh, oacc[nt], 0, 0, 0);
      oacc[nt] = __builtin_amdgcn_mfma_f32_32x32x16_bf16(vh, pbl, oacc[nt], 0, 0, 0);
      oacc[nt] = __builtin_amdgcn_mfma_f32_32x32x16_bf16(vl, pbh, oacc[nt], 0, 0, 0);
    }
  }

  // ---- epilogue: out^T value (nt, r): d = 4hi + (r&3) + 8(r>>2), q pixel = pix(nt) ----
  const size_t ocb = (size_t)(b * 192 + nh * 32) * HWSZ;
#pragma unroll
  for (int r = 0; r < 16; ++r) {
    const int d = 4*hi + (r & 3) + 8*(r >> 2);
    out[ocb + (size_t)d * HWSZ + pix0] = oacc[0][r] * rs0;
    out[ocb + (size_t)d * HWSZ + pix1] = oacc[1][r] * rs1;
  }
}

extern "C" void kernel_launch(void* const* d_in, const int* in_sizes, int n_in,
                              void* d_out, int out_size, void* d_ws, size_t ws_size,
                              hipStream_t stream) {
  const float* x   = (const float*)d_in[0];
  const float* rpb = (const float*)d_in[1];
  float* out = (float*)d_out;
  dim3 grid(4 * 32 * 32 * NH);   // (b, wh, nh, ww), ww fastest
  dim3 block(64);
  hipLaunchKernelGGL(swin_attn_mfma, grid, block, 0, stream, x, rpb, out);
}

// Round 8
// 939.812 us; speedup vs baseline: 1.1790x; 1.0707x over previous
//
#include <hip/hip_runtime.h>

#define NH 6
#define HWSZ 65536
#define SCALE 0.17677669529663687f  // 32^-0.5

typedef __attribute__((ext_vector_type(8)))  short short8t;   // 8 bf16 = 4 VGPR (MFMA frag)
typedef __attribute__((ext_vector_type(16))) float f32x16;    // MFMA 32x32 accumulator
typedef __attribute__((ext_vector_type(4)))  unsigned int uint4t;

__device__ __forceinline__ unsigned int pack2(float a, float b) {
  return (__float_as_uint(a) >> 16) | (__float_as_uint(b) & 0xffff0000u);
}
__device__ __forceinline__ float btrunc_f(float a) {
  return __uint_as_float(__float_as_uint(a) & 0xffff0000u);
}
__device__ __forceinline__ float resid(float a) { return a - btrunc_f(a); }

__device__ __forceinline__ void split8(const float (&f)[8], short8t& h, short8t& l) {
  uint4t hw, lw;
#pragma unroll
  for (int i = 0; i < 4; ++i) {
    const float a = f[2*i], c = f[2*i+1];
    hw[i] = pack2(a, c);
    lw[i] = pack2(resid(a), resid(c));
  }
  h = __builtin_bit_cast(short8t, hw);
  l = __builtin_bit_cast(short8t, lw);
}

// 256-thread block = 4 independent waves = 4 consecutive ww windows, same (b,wh,nh).
// Per wave: swapped-operand MFMA attention (att^T = K·Q^T ; out^T = V^T·P^T).
// No __syncthreads: V slice is wave-private, rpb writes idempotent across waves.
// V LDS layout: f = d*64 + slot'*4 + u, slot' = (s>>2) ^ (d&7)  -> 4-way read conflict.
__global__ __launch_bounds__(256, 4)
void swin_attn_mfma4(const float* __restrict__ x,
                     const float* __restrict__ rpb,
                     float* __restrict__ out) {
  __shared__ float Vt[4][2048];
  __shared__ float rpb_s[232];

  // XCD-chunked bijective swizzle over 6144 blocks (6144 % 8 == 0)
  const int raw = (int)blockIdx.x;
  const int lid = (raw & 7) * 768 + (raw >> 3);
  const int wwg = lid & 7;
  int t = lid >> 3;
  const int nh = t % NH; t /= NH;
  const int wh = t & 31;
  const int b  = t >> 5;

  const int tid  = (int)threadIdx.x;
  const int wid  = tid >> 6;
  const int lane = tid & 63;
  const int ww   = wwg * 4 + wid;
  const int lo = lane & 31, hi = lane >> 5;

  float* vslice = &Vt[wid][0];

  // ---- V staging: dest linear, source pre-swizzled (slot XOR) ----
  // dest float p = i*256 + lane*4 + u : d = i*4 + (lane>>4), slot' = lane&15
  // content s = ((lane&15) ^ (d&7))*4 + u ; d&7 = 4*(i&1) + (lane>>4)
  {
    const int dly = lane >> 4;            // 0..3
    const int sl  = lane & 15;
    const int se  = (sl ^ dly) << 2;            // even i
    const int so  = (sl ^ (4 + dly)) << 2;      // odd i
    const size_t cb = (size_t)(b * 576 + 384 + nh * 32 + dly) * HWSZ;
    const float* gve = x + cb + (size_t)(((wh*8+4+(se>>3)) & 255) * 256 + ((ww*8+4+(se&7)) & 255));
    const float* gvo = x + cb + (size_t)(((wh*8+4+(so>>3)) & 255) * 256 + ((ww*8+4+(so&7)) & 255));
#pragma unroll
    for (int i = 0; i < 8; ++i) {
      const float* src = (i & 1) ? gvo : gve;
      __builtin_amdgcn_global_load_lds(
          (const __attribute__((address_space(1))) void*)(src + (size_t)i * 4 * HWSZ),
          (__attribute__((address_space(3))) void*)(&vslice[i * 256]), 16, 0, 0);
    }
  }
  // rpb column (idempotent: all 4 waves write identical values)
  for (int r = lane; r < 225; r += 64) rpb_s[r] = rpb[r * NH + nh];

  // ---- pixel coords ----
  const int iy = lo >> 3, ix = lo & 7;
  const int sh0 = (wh*8 + 4 + iy) & 255;
  const int sh1 = (wh*8 + 8 + iy) & 255;
  const int sw  = (ww*8 + 4 + ix) & 255;
  const size_t pix0 = (size_t)sh0 * 256 + sw;
  const size_t pix1 = (size_t)sh1 * 256 + sw;
  const size_t qcb = (size_t)(b * 576 + nh * 32) * HWSZ;
  const size_t kcb = qcb + (size_t)192 * HWSZ;

  // ---- Q/K fragments straight from global ----
  short8t qh[2][2], ql[2][2], kh[2][2], kl[2][2];   // [ks][tile]
#pragma unroll
  for (int ks = 0; ks < 2; ++ks) {
#pragma unroll
    for (int tt = 0; tt < 2; ++tt) {
      const size_t pp = tt ? pix1 : pix0;
      float f[8], g[8];
#pragma unroll
      for (int e = 0; e < 8; ++e) {
        const size_t dof = (size_t)(ks*16 + hi*8 + e) * HWSZ;
        f[e] = x[qcb + dof + pp];
        g[e] = x[kcb + dof + pp];
      }
      split8(f, qh[ks][tt], ql[ks][tt]);
      split8(g, kh[ks][tt], kl[ks][tt]);
    }
  }

  // ---- QK^T with 3-product fp32 emulation ----
  f32x16 acc[2][2];
#pragma unroll
  for (int mt = 0; mt < 2; ++mt)
#pragma unroll
    for (int nt = 0; nt < 2; ++nt)
#pragma unroll
      for (int r = 0; r < 16; ++r) acc[mt][nt][r] = 0.f;

#pragma unroll
  for (int ks = 0; ks < 2; ++ks)
#pragma unroll
    for (int mt = 0; mt < 2; ++mt)
#pragma unroll
      for (int nt = 0; nt < 2; ++nt) {
        acc[mt][nt] = __builtin_amdgcn_mfma_f32_32x32x16_bf16(kh[ks][mt], qh[ks][nt], acc[mt][nt], 0, 0, 0);
        acc[mt][nt] = __builtin_amdgcn_mfma_f32_32x32x16_bf16(kh[ks][mt], ql[ks][nt], acc[mt][nt], 0, 0, 0);
        acc[mt][nt] = __builtin_amdgcn_mfma_f32_32x32x16_bf16(kl[ks][mt], qh[ks][nt], acc[mt][nt], 0, 0, 0);
      }

  // ---- scale + rpb (+ shift mask only on edge windows; wave-uniform branch) ----
  const bool eh = (wh == 31), ew = (ww == 31);
  float mrow[2] = {-1e30f, -1e30f};
  if (!eh && !ew) {
#pragma unroll
    for (int nt = 0; nt < 2; ++nt) {
      const int qoff = (4*nt + iy + 7) * 15 + (ix + 7);
#pragma unroll
      for (int mt = 0; mt < 2; ++mt)
#pragma unroll
        for (int r = 0; r < 16; ++r) {
          const int koff = (4*mt + (r >> 2)) * 15 + 4*hi + (r & 3);
          const float a = fmaf(acc[mt][nt][r], SCALE, rpb_s[qoff - koff]);
          acc[mt][nt][r] = a;
          mrow[nt] = fmaxf(mrow[nt], a);
        }
    }
  } else {
#pragma unroll
    for (int nt = 0; nt < 2; ++nt) {
      const int qyy = 4*nt + iy;
      const int rq = (eh ? 1 + (qyy >> 2) : 0) * 3 + (ew ? 1 + (ix >> 2) : 0);
      const int qoff = (qyy + 7) * 15 + (ix + 7);
#pragma unroll
      for (int mt = 0; mt < 2; ++mt)
#pragma unroll
        for (int r = 0; r < 16; ++r) {
          const int ky = 4*mt + (r >> 2);
          const int kx = 4*hi + (r & 3);
          float a = fmaf(acc[mt][nt][r], SCALE, rpb_s[qoff - ky*15 - kx]);
          const int rk = (eh ? 1 + (ky >> 2) : 0) * 3 + (ew ? 1 + (kx >> 2) : 0);
          a += (rk == rq) ? 0.f : -100.f;
          acc[mt][nt][r] = a;
          mrow[nt] = fmaxf(mrow[nt], a);
        }
    }
  }
  mrow[0] = fmaxf(mrow[0], __shfl_xor(mrow[0], 32));
  mrow[1] = fmaxf(mrow[1], __shfl_xor(mrow[1], 32));

  float sum0 = 0.f, sum1 = 0.f;
#pragma unroll
  for (int mt = 0; mt < 2; ++mt)
#pragma unroll
    for (int r = 0; r < 16; ++r) {
      const float p0 = __expf(acc[mt][0][r] - mrow[0]);
      const float p1 = __expf(acc[mt][1][r] - mrow[1]);
      acc[mt][0][r] = p0; sum0 += p0;
      acc[mt][1][r] = p1; sum1 += p1;
    }
  sum0 += __shfl_xor(sum0, 32);
  sum1 += __shfl_xor(sum1, 32);
  const float rs0 = 1.f / sum0, rs1 = 1.f / sum1;

  // ---- ensure V staging landed (global_load_lds tracked by vmcnt only) ----
  asm volatile("s_waitcnt vmcnt(0)" ::: "memory");

  // ---- PV: out^T = V^T · P^T ----
  f32x16 oacc[2];
#pragma unroll
  for (int r = 0; r < 16; ++r) { oacc[0][r] = 0.f; oacc[1][r] = 0.f; }

#pragma unroll
  for (int ks2 = 0; ks2 < 4; ++ks2) {
    const int mt = ks2 >> 1, bs = (ks2 & 1) * 8;
    // V A-frag: element e -> V[s=16ks2+8hi+e][d=lo]; slot' = (s>>2) ^ (lo&7)
    float vf[8];
    {
      const int sp0 = ((4*ks2 + 2*hi)     ^ (lo & 7)) * 4;
      const int sp1 = ((4*ks2 + 2*hi + 1) ^ (lo & 7)) * 4;
      const float4 v0 = *(const float4*)&vslice[lo*64 + sp0];
      const float4 v1 = *(const float4*)&vslice[lo*64 + sp1];
      vf[0]=v0.x; vf[1]=v0.y; vf[2]=v0.z; vf[3]=v0.w;
      vf[4]=v1.x; vf[5]=v1.y; vf[6]=v1.z; vf[7]=v1.w;
    }
    short8t vh, vl; split8(vf, vh, vl);
#pragma unroll
    for (int nt = 0; nt < 2; ++nt) {
      const float a0 = acc[mt][nt][bs+0], a1 = acc[mt][nt][bs+1];
      const float a2 = acc[mt][nt][bs+2], a3 = acc[mt][nt][bs+3];
      const float b0 = acc[mt][nt][bs+4], b1 = acc[mt][nt][bs+5];
      const float b2 = acc[mt][nt][bs+6], b3 = acc[mt][nt][bs+7];
      const unsigned int Ah0 = pack2(a0, a1), Ah1 = pack2(a2, a3);
      const unsigned int Bh0 = pack2(b0, b1), Bh1 = pack2(b2, b3);
      const unsigned int Al0 = pack2(resid(a0), resid(a1)), Al1 = pack2(resid(a2), resid(a3));
      const unsigned int Bl0 = pack2(resid(b0), resid(b1)), Bl1 = pack2(resid(b2), resid(b3));
      const unsigned int xAh0 = __shfl_xor(Ah0, 32), xAh1 = __shfl_xor(Ah1, 32);
      const unsigned int xBh0 = __shfl_xor(Bh0, 32), xBh1 = __shfl_xor(Bh1, 32);
      const unsigned int xAl0 = __shfl_xor(Al0, 32), xAl1 = __shfl_xor(Al1, 32);
      const unsigned int xBl0 = __shfl_xor(Bl0, 32), xBl1 = __shfl_xor(Bl1, 32);
      uint4t wh4, wl4;
      wh4[0] = hi ? xBh0 : Ah0;  wh4[1] = hi ? xBh1 : Ah1;
      wh4[2] = hi ? Bh0 : xAh0;  wh4[3] = hi ? Bh1 : xAh1;
      wl4[0] = hi ? xBl0 : Al0;  wl4[1] = hi ? xBl1 : Al1;
      wl4[2] = hi ? Bl0 : xAl0;  wl4[3] = hi ? Bl1 : xAl1;
      const short8t pbh = __builtin_bit_cast(short8t, wh4);
      const short8t pbl = __builtin_bit_cast(short8t, wl4);
      oacc[nt] = __builtin_amdgcn_mfma_f32_32x32x16_bf16(vh, pbh, oacc[nt], 0, 0, 0);
      oacc[nt] = __builtin_amdgcn_mfma_f32_32x32x16_bf16(vh, pbl, oacc[nt], 0, 0, 0);
      oacc[nt] = __builtin_amdgcn_mfma_f32_32x32x16_bf16(vl, pbh, oacc[nt], 0, 0, 0);
    }
  }

  // ---- epilogue: d = 4hi + (r&3) + 8(r>>2) ----
  const size_t ocb = (size_t)(b * 192 + nh * 32) * HWSZ;
#pragma unroll
  for (int r = 0; r < 16; ++r) {
    const int d = 4*hi + (r & 3) + 8*(r >> 2);
    out[ocb + (size_t)d * HWSZ + pix0] = oacc[0][r] * rs0;
    out[ocb + (size_t)d * HWSZ + pix1] = oacc[1][r] * rs1;
  }
}

extern "C" void kernel_launch(void* const* d_in, const int* in_sizes, int n_in,
                              void* d_out, int out_size, void* d_ws, size_t ws_size,
                              hipStream_t stream) {
  const float* x   = (const float*)d_in[0];
  const float* rpb = (const float*)d_in[1];
  float* out = (float*)d_out;
  dim3 grid(4 * 32 * NH * 8);   // 6144 blocks: (b, wh, nh, wwg)
  dim3 block(256);              // 4 waves = 4 consecutive ww windows
  hipLaunchKernelGGL(swin_attn_mfma4, grid, block, 0, stream, x, rpb, out);
}